// Round 12
// baseline (359.815 us; speedup 1.0000x reference)
//
#include <hip/hip_runtime.h>

typedef short short8 __attribute__((ext_vector_type(8)));
typedef float f32x4 __attribute__((ext_vector_type(4)));
typedef unsigned int uint;

#define C_IN  128
#define H_IN  112
#define W_IN  112
#define K_OUT 256
#define H_OUTD 110
#define W_OUTD 110
#define NBATCH 32

// xT layout: [n][h][w][cpos(128)] bf16, cpos = (c&64) | ((c&63) ^ ((w&7)<<3))
#define XT_ELEMS (NBATCH*H_IN*W_IN*128)    // 51,380,224
// F2 layout: [S(36)][f(16)][lane(64)][e(8)], S = ph*18 + rs*2 + ch2
//   k = f*16+(lane&15) ; c = ph*64 + ch2*32 + (lane>>4)*8 + e
#define F_ELEMS  (36*16*64*8)              // 294,912

__device__ __forceinline__ unsigned short f2bf(float f) {
  uint u = __float_as_uint(f);
  u += 0x7fffu + ((u >> 16) & 1u);   // RNE
  return (unsigned short)(u >> 16);
}

__device__ __forceinline__ void gll16(const unsigned short* g, unsigned short* l) {
  __builtin_amdgcn_global_load_lds(
      (const __attribute__((address_space(1))) void*)g,
      (__attribute__((address_space(3))) void*)(uint)(uintptr_t)l, 16, 0, 0);
}

// ---------------- prep: x (NCHW f32) -> xT (swizzled bf16) ----------------
__global__ __launch_bounds__(256) void xpose_kernel(const float* __restrict__ x,
                                                    unsigned short* __restrict__ xT) {
  __shared__ unsigned short sm[H_IN * 128];   // [w][cpos] 28,672 B
  const int n = blockIdx.y;
  const int h = blockIdx.x;
  const int tid = threadIdx.x;
  for (int it = 0; it < 28; ++it) {
    int idx = it*256 + tid;            // 0..7167  (64 c-pairs x 112 w)
    int w  = idx % 112;
    int cp = idx / 112;                // 0..63
    int c0 = cp*2;
    const float* px = x + ((size_t)(n*C_IN + c0)*H_IN + h)*W_IN + w;
    float f0 = px[0];
    float f1 = px[H_IN*W_IN];
    uint key  = ((uint)w & 7u) << 3;
    uint cpos = ((uint)c0 & 64u) | (((uint)c0 & 63u) ^ key);
    uint v = (uint)f2bf(f0) | ((uint)f2bf(f1) << 16);
    *(uint*)&sm[w*128 + cpos] = v;
  }
  __syncthreads();
  for (int it = 0; it < 7; ++it) {
    int idx = it*256 + tid;            // 0..1791 chunks of 8 shorts
    int w  = idx >> 4;
    int cc = idx & 15;
    uint4 v = *(const uint4*)&sm[w*128 + cc*8];
    size_t off = (((size_t)n*H_IN + h)*W_IN + w)*128 + cc*8;
    *(uint4*)&xT[off] = v;
  }
}

// ---- prep: filt (OIHW f32) -> F2 fragment-packed bf16 (ph-major slices) ----
__global__ __launch_bounds__(256) void fprep_kernel(const float* __restrict__ ft,
                                                    unsigned short* __restrict__ F) {
  int idx = blockIdx.x*256 + threadIdx.x;   // < 294912
  int e    = idx & 7;
  int lane = (idx >> 3) & 63;
  int f    = (idx >> 9) & 15;
  int S    = idx >> 13;                     // 0..35
  int ph   = S >= 18;
  int j    = S - ph*18;
  int rs   = j >> 1;
  int ch2  = j & 1;
  int k = f*16 + (lane & 15);
  int c = ph*64 + ch2*32 + (lane >> 4)*8 + e;
  F[idx] = f2bf(ft[(k*C_IN + c)*9 + rs]);
}

// ---------------- main implicit-GEMM conv: 1-barrier/step counted-vmcnt ----------------
// block: 512 thr (8 waves, 2M x 4N), output tile = 256 K_out x (16h x 16w)
// wave = 128k x 64px (8 mt x 4 nt of 16x16x32 frags), acc = 128 regs
// smX: full 18x18x128 halo [ph(2)][cell(324)][64] = 82,944 B, staged ONCE
// smA: 4-slice x 16 KB ring of fragment-packed F; both halves issued at step top.
// ONE barrier per step (end, after counted vmcnt(2)): waves de-synchronize
// within the step so ds_reads of late waves stream under MFMAs of early waves.
// Ledger: at end of step i outstanding = {L_{i+1}a,b, L_{i+2}a,b}; vmcnt(2)
// retires slice i+1 -> step i+1 reads safe. vmcnt(0) at i>=34 (tail).
__global__ __launch_bounds__(512, 2) void conv_gemm(const unsigned short* __restrict__ xT,
                                                    const unsigned short* __restrict__ F,
                                                    float* __restrict__ out) {
  __shared__ unsigned short smX[2*324*64];    // 82,944 B
  __shared__ unsigned short smA[4*8192];      // 65,536 B
  // bijective XCD swizzle: 1568 blocks = 8 XCDs x 196
  const int bid  = blockIdx.y*49 + blockIdx.x;
  const int wgid = (bid & 7)*196 + (bid >> 3);
  const int tile = wgid % 49;                 // 7 h-tiles x 7 w-tiles
  const int n    = wgid / 49;
  const int tid  = threadIdx.x;
  const int lane = tid & 63;
  const int wid  = tid >> 6;
  const int wm2  = wid & 1;                   // M half (128 k each)
  const int wn4  = wid >> 1;                  // N quarter (4 h-rows each)
  const int l15  = lane & 15;
  const int lhi  = lane >> 4;                 // 0..3
  const int th   = tile / 7;
  const int tw   = tile - th*7;
  const int h0   = th*16;
  const int w0   = tw*16;

  int browb[4];
  #pragma unroll
  for (int nt = 0; nt < 4; ++nt)
    browb[nt] = ((wn4*4 + nt)*18 + l15)*64;   // halo cell * 64 shorts

  f32x4 acc[8][4];
  #pragma unroll
  for (int mt = 0; mt < 8; ++mt)
    #pragma unroll
    for (int nt = 0; nt < 4; ++nt)
      acc[mt][nt] = (f32x4){0.f, 0.f, 0.f, 0.f};

  // ---- prologue: stage full halo + slices 0,1 ----
  {
    const unsigned short* xbase = xT + (size_t)n*H_IN*W_IN*128;
    #pragma unroll
    for (int k = 0; k < 11; ++k) {
      int ci = k*512 + tid;                   // < 5184 chunks of 16 B
      if (ci < 5184) {
        int ph  = ci >= 2592;
        int rem = ci - ph*2592;
        int cell = rem >> 3, sub = rem & 7;
        int hh = cell / 18, ww = cell - hh*18;
        int hc = h0 + hh; if (hc > 111) hc = 111;
        int wc = w0 + ww; if (wc > 111) wc = 111;
        gll16(xbase + ((size_t)(hc*W_IN + wc))*128 + ph*64 + sub*8, &smX[ci*8]);
      }
    }
    gll16(F + tid*8,               &smA[tid*8]);
    gll16(F + 4096 + tid*8,        &smA[4096 + tid*8]);
    gll16(F + 8192 + tid*8,        &smA[8192 + tid*8]);
    gll16(F + 8192 + 4096 + tid*8, &smA[8192 + 4096 + tid*8]);
  }
  __syncthreads();                            // full drain, once

  const unsigned short* Fs  = F + tid*8;
  unsigned short* smAt      = smA + tid*8;

  #pragma unroll
  for (int i = 0; i < 36; ++i) {
    const int ph  = (i >= 18);
    const int jj  = i - ph*18;
    const int rs  = jj >> 1, ch2 = jj & 1;
    const int r   = rs/3, s = rs - r*3;
    const int key = ((l15 + s) & 7) << 3;
    const int boff = ph*20736 + (r*18 + s)*64 + ((ch2*32 + lhi*8) ^ key);
    const int ab   = (i & 3)*8192 + wm2*4096 + lane*8;

    // issue both halves of slice i+2 at step top (max flight time)
    if (i + 2 < 36) {
      gll16(Fs + (i + 2)*8192,        smAt + ((i + 2) & 3)*8192);
      gll16(Fs + (i + 2)*8192 + 4096, smAt + ((i + 2) & 3)*8192 + 4096);
    }

    // ---- half 1: read b0-3, a0-3; 16 MFMA ----
    short8 b0 = *(const short8*)&smX[browb[0] + boff];
    short8 b1 = *(const short8*)&smX[browb[1] + boff];
    short8 b2 = *(const short8*)&smX[browb[2] + boff];
    short8 b3 = *(const short8*)&smX[browb[3] + boff];
    short8 a0 = *(const short8*)&smA[ab];
    short8 a1 = *(const short8*)&smA[ab + 512];
    short8 a2 = *(const short8*)&smA[ab + 1024];
    short8 a3 = *(const short8*)&smA[ab + 1536];
    __builtin_amdgcn_s_setprio(1);
    acc[0][0] = __builtin_amdgcn_mfma_f32_16x16x32_bf16(a0, b0, acc[0][0], 0, 0, 0);
    acc[0][1] = __builtin_amdgcn_mfma_f32_16x16x32_bf16(a0, b1, acc[0][1], 0, 0, 0);
    acc[0][2] = __builtin_amdgcn_mfma_f32_16x16x32_bf16(a0, b2, acc[0][2], 0, 0, 0);
    acc[0][3] = __builtin_amdgcn_mfma_f32_16x16x32_bf16(a0, b3, acc[0][3], 0, 0, 0);
    acc[1][0] = __builtin_amdgcn_mfma_f32_16x16x32_bf16(a1, b0, acc[1][0], 0, 0, 0);
    acc[1][1] = __builtin_amdgcn_mfma_f32_16x16x32_bf16(a1, b1, acc[1][1], 0, 0, 0);
    acc[1][2] = __builtin_amdgcn_mfma_f32_16x16x32_bf16(a1, b2, acc[1][2], 0, 0, 0);
    acc[1][3] = __builtin_amdgcn_mfma_f32_16x16x32_bf16(a1, b3, acc[1][3], 0, 0, 0);
    acc[2][0] = __builtin_amdgcn_mfma_f32_16x16x32_bf16(a2, b0, acc[2][0], 0, 0, 0);
    acc[2][1] = __builtin_amdgcn_mfma_f32_16x16x32_bf16(a2, b1, acc[2][1], 0, 0, 0);
    acc[2][2] = __builtin_amdgcn_mfma_f32_16x16x32_bf16(a2, b2, acc[2][2], 0, 0, 0);
    acc[2][3] = __builtin_amdgcn_mfma_f32_16x16x32_bf16(a2, b3, acc[2][3], 0, 0, 0);
    acc[3][0] = __builtin_amdgcn_mfma_f32_16x16x32_bf16(a3, b0, acc[3][0], 0, 0, 0);
    acc[3][1] = __builtin_amdgcn_mfma_f32_16x16x32_bf16(a3, b1, acc[3][1], 0, 0, 0);
    acc[3][2] = __builtin_amdgcn_mfma_f32_16x16x32_bf16(a3, b2, acc[3][2], 0, 0, 0);
    acc[3][3] = __builtin_amdgcn_mfma_f32_16x16x32_bf16(a3, b3, acc[3][3], 0, 0, 0);
    __builtin_amdgcn_s_setprio(0);

    // ---- half 2: read a4-7; 16 MFMA (no barrier between halves) ----
    short8 a4 = *(const short8*)&smA[ab + 2048];
    short8 a5 = *(const short8*)&smA[ab + 2560];
    short8 a6 = *(const short8*)&smA[ab + 3072];
    short8 a7 = *(const short8*)&smA[ab + 3584];
    __builtin_amdgcn_s_setprio(1);
    acc[4][0] = __builtin_amdgcn_mfma_f32_16x16x32_bf16(a4, b0, acc[4][0], 0, 0, 0);
    acc[4][1] = __builtin_amdgcn_mfma_f32_16x16x32_bf16(a4, b1, acc[4][1], 0, 0, 0);
    acc[4][2] = __builtin_amdgcn_mfma_f32_16x16x32_bf16(a4, b2, acc[4][2], 0, 0, 0);
    acc[4][3] = __builtin_amdgcn_mfma_f32_16x16x32_bf16(a4, b3, acc[4][3], 0, 0, 0);
    acc[5][0] = __builtin_amdgcn_mfma_f32_16x16x32_bf16(a5, b0, acc[5][0], 0, 0, 0);
    acc[5][1] = __builtin_amdgcn_mfma_f32_16x16x32_bf16(a5, b1, acc[5][1], 0, 0, 0);
    acc[5][2] = __builtin_amdgcn_mfma_f32_16x16x32_bf16(a5, b2, acc[5][2], 0, 0, 0);
    acc[5][3] = __builtin_amdgcn_mfma_f32_16x16x32_bf16(a5, b3, acc[5][3], 0, 0, 0);
    acc[6][0] = __builtin_amdgcn_mfma_f32_16x16x32_bf16(a6, b0, acc[6][0], 0, 0, 0);
    acc[6][1] = __builtin_amdgcn_mfma_f32_16x16x32_bf16(a6, b1, acc[6][1], 0, 0, 0);
    acc[6][2] = __builtin_amdgcn_mfma_f32_16x16x32_bf16(a6, b2, acc[6][2], 0, 0, 0);
    acc[6][3] = __builtin_amdgcn_mfma_f32_16x16x32_bf16(a6, b3, acc[6][3], 0, 0, 0);
    acc[7][0] = __builtin_amdgcn_mfma_f32_16x16x32_bf16(a7, b0, acc[7][0], 0, 0, 0);
    acc[7][1] = __builtin_amdgcn_mfma_f32_16x16x32_bf16(a7, b1, acc[7][1], 0, 0, 0);
    acc[7][2] = __builtin_amdgcn_mfma_f32_16x16x32_bf16(a7, b2, acc[7][2], 0, 0, 0);
    acc[7][3] = __builtin_amdgcn_mfma_f32_16x16x32_bf16(a7, b3, acc[7][3], 0, 0, 0);
    __builtin_amdgcn_s_setprio(0);

    // ---- end-of-step: counted wait + single barrier ----
    if (i < 35) {
      if (i >= 34) asm volatile("s_waitcnt vmcnt(0)" ::: "memory");
      else         asm volatile("s_waitcnt vmcnt(2)" ::: "memory");
      __builtin_amdgcn_s_barrier();
      __builtin_amdgcn_sched_barrier(0);
    }
  }

  // epilogue: D frag: col(px)=l15, row(k)=lhi*4+reg
  const int wv = w0 + l15;
  #pragma unroll
  for (int nt = 0; nt < 4; ++nt) {
    int hv = h0 + wn4*4 + nt;
    if (hv < H_OUTD && wv < W_OUTD) {
      float* po = out + (size_t)n*K_OUT*(H_OUTD*W_OUTD) + hv*W_OUTD + wv;
      #pragma unroll
      for (int mt = 0; mt < 8; ++mt) {
        #pragma unroll
        for (int reg = 0; reg < 4; ++reg) {
          int k = wm2*128 + mt*16 + lhi*4 + reg;
          po[(size_t)k*(H_OUTD*W_OUTD)] = acc[mt][nt][reg];
        }
      }
    }
  }
}

// ---------------- fallback (ws too small): naive fp32 ----------------
__global__ void naive_conv(const float* __restrict__ x, const float* __restrict__ ft,
                           float* __restrict__ out) {
  int idx = blockIdx.x*256 + threadIdx.x;
  int total = NBATCH*K_OUT*H_OUTD*W_OUTD;
  if (idx >= total) return;
  int w = idx % W_OUTD; int t = idx / W_OUTD;
  int h = t % H_OUTD; t /= H_OUTD;
  int k = t % K_OUT; int nn = t / K_OUT;
  float acc = 0.f;
  for (int c = 0; c < C_IN; ++c)
    for (int r = 0; r < 3; ++r)
      for (int s = 0; s < 3; ++s)
        acc += x[((size_t)(nn*C_IN + c)*H_IN + h + r)*W_IN + w + s]
             * ft[((k*C_IN + c)*3 + r)*3 + s];
  out[idx] = acc;
}

extern "C" void kernel_launch(void* const* d_in, const int* in_sizes, int n_in,
                              void* d_out, int out_size, void* d_ws, size_t ws_size,
                              hipStream_t stream) {
  (void)in_sizes; (void)n_in; (void)out_size;
  const float* x  = (const float*)d_in[0];
  const float* ft = (const float*)d_in[1];
  float* out = (float*)d_out;
  size_t need = (size_t)(XT_ELEMS + F_ELEMS) * sizeof(unsigned short);
  if (ws_size >= need) {
    unsigned short* xT = (unsigned short*)d_ws;
    unsigned short* F  = xT + XT_ELEMS;
    xpose_kernel<<<dim3(112, 32), 256, 0, stream>>>(x, xT);
    fprep_kernel<<<dim3(1152), 256, 0, stream>>>(ft, F);
    conv_gemm<<<dim3(49, 32), 512, 0, stream>>>(xT, F, out);
  } else {
    int total = NBATCH*K_OUT*H_OUTD*W_OUTD;
    naive_conv<<<(total + 255)/256, 256, 0, stream>>>(x, ft, out);
  }
}

// Round 13
// 346.834 us; speedup vs baseline: 1.0374x; 1.0374x over previous
//
#include <hip/hip_runtime.h>

typedef short short8 __attribute__((ext_vector_type(8)));
typedef float f32x4 __attribute__((ext_vector_type(4)));
typedef unsigned int uint;

#define C_IN  128
#define H_IN  112
#define W_IN  112
#define K_OUT 256
#define H_OUTD 110
#define W_OUTD 110
#define NBATCH 32

// xT layout: [n][h][w][cpos(128)] bf16, cpos = (c&64) | ((c&63) ^ ((w&7)<<3))
#define XT_ELEMS (NBATCH*H_IN*W_IN*128)    // 51,380,224
// F2 layout: [S(36)][wm(4)][mt(4)][lane(64)][e(8)], S = ph*18 + rs*2 + ch2
//   k = wm*64+mt*16+(lane&15) ; c = ph*64 + ch2*32 + (lane>>4)*8 + e
#define F_ELEMS  (36*4*4*64*8)             // 294,912

__device__ __forceinline__ unsigned short f2bf(float f) {
  uint u = __float_as_uint(f);
  u += 0x7fffu + ((u >> 16) & 1u);   // RNE
  return (unsigned short)(u >> 16);
}

__device__ __forceinline__ void gll16(const unsigned short* g, unsigned short* l) {
  __builtin_amdgcn_global_load_lds(
      (const __attribute__((address_space(1))) void*)g,
      (__attribute__((address_space(3))) void*)(uint)(uintptr_t)l, 16, 0, 0);
}

// ---------------- prep: x (NCHW f32) -> xT (swizzled bf16) ----------------
__global__ __launch_bounds__(256) void xpose_kernel(const float* __restrict__ x,
                                                    unsigned short* __restrict__ xT) {
  __shared__ unsigned short sm[H_IN * 128];   // [w][cpos] 28,672 B
  const int n = blockIdx.y;
  const int h = blockIdx.x;
  const int tid = threadIdx.x;
  for (int it = 0; it < 28; ++it) {
    int idx = it*256 + tid;            // 0..7167  (64 c-pairs x 112 w)
    int w  = idx % 112;
    int cp = idx / 112;                // 0..63
    int c0 = cp*2;
    const float* px = x + ((size_t)(n*C_IN + c0)*H_IN + h)*W_IN + w;
    float f0 = px[0];
    float f1 = px[H_IN*W_IN];
    uint key  = ((uint)w & 7u) << 3;
    uint cpos = ((uint)c0 & 64u) | (((uint)c0 & 63u) ^ key);
    uint v = (uint)f2bf(f0) | ((uint)f2bf(f1) << 16);
    *(uint*)&sm[w*128 + cpos] = v;
  }
  __syncthreads();
  for (int it = 0; it < 7; ++it) {
    int idx = it*256 + tid;            // 0..1791 chunks of 8 shorts
    int w  = idx >> 4;
    int cc = idx & 15;
    uint4 v = *(const uint4*)&sm[w*128 + cc*8];
    size_t off = (((size_t)n*H_IN + h)*W_IN + w)*128 + cc*8;
    *(uint4*)&xT[off] = v;
  }
}

// ---- prep: filt (OIHW f32) -> F2 fragment-packed bf16 (ph-major slices) ----
__global__ __launch_bounds__(256) void fprep_kernel(const float* __restrict__ ft,
                                                    unsigned short* __restrict__ F) {
  int idx = blockIdx.x*256 + threadIdx.x;   // < 294912
  int e    = idx & 7;
  int lane = (idx >> 3) & 63;
  int mt   = (idx >> 9) & 3;
  int wm   = (idx >> 11) & 3;
  int S    = idx >> 13;                     // 0..35
  int ph   = S >= 18;
  int j    = S - ph*18;
  int rs   = j >> 1;
  int ch2  = j & 1;
  int k = wm*64 + mt*16 + (lane & 15);
  int c = ph*64 + ch2*32 + (lane >> 4)*8 + e;
  F[idx] = f2bf(ft[(k*C_IN + c)*9 + rs]);
}

// ---------------- main implicit-GEMM conv: cross-step reg pipeline ----------------
// block: 512 thr (8 waves, 4M x 2N), output tile = 256 K_out x (16h x 16w)
// wave = 64k x 128px (4 mt x 8 nt of 16x16x32 frags), acc = 128 regs
// smX: full 18x18x128 halo [ph(2)][cell(324)][64] = 82,944 B, staged ONCE;
// NO barriers in K-loop. A: fragment-packed F (L2-resident) global->reg;
// B: halo ds_read->reg. BOTH streams double-buffered one step ahead so the
// lgkmcnt/vmcnt waits land a full MFMA cluster after issue (LDS/MFMA overlap).
__global__ __launch_bounds__(512, 2) void conv_gemm(const unsigned short* __restrict__ xT,
                                                    const unsigned short* __restrict__ F,
                                                    float* __restrict__ out) {
  __shared__ unsigned short smX[2*324*64];    // 82,944 B
  // bijective XCD swizzle: 1568 blocks = 8 XCDs x 196
  const int bid  = blockIdx.y*49 + blockIdx.x;
  const int wgid = (bid & 7)*196 + (bid >> 3);
  const int tile = wgid % 49;                 // 7 h-tiles x 7 w-tiles
  const int n    = wgid / 49;
  const int tid  = threadIdx.x;
  const int lane = tid & 63;
  const int wid  = tid >> 6;
  const int wm   = wid & 3;                   // M quadrant (64 k each)
  const int wn   = wid >> 2;                  // N half (8 h-rows each)
  const int l15  = lane & 15;
  const int lhi  = lane >> 4;                 // 0..3
  const int th   = tile / 7;
  const int tw   = tile - th*7;
  const int h0   = th*16;
  const int w0   = tw*16;

  int browb[8];
  #pragma unroll
  for (int nt = 0; nt < 8; ++nt)
    browb[nt] = ((wn*8 + nt)*18 + l15)*64;    // halo cell * 64 shorts

  f32x4 acc[4][8];
  #pragma unroll
  for (int mt = 0; mt < 4; ++mt)
    #pragma unroll
    for (int nt = 0; nt < 8; ++nt)
      acc[mt][nt] = (f32x4){0.f, 0.f, 0.f, 0.f};

  // stage full halo: 5184 chunks of 16B -> smX[ph][cell][64]
  {
    const unsigned short* xbase = xT + (size_t)n*H_IN*W_IN*128;
    #pragma unroll
    for (int k = 0; k < 11; ++k) {
      int ci = k*512 + tid;
      if (ci < 5184) {
        int ph  = ci >= 2592;
        int rem = ci - ph*2592;
        int cell = rem >> 3, sub = rem & 7;
        int hh = cell / 18, ww = cell - hh*18;
        int hc = h0 + hh; if (hc > 111) hc = 111;
        int wc = w0 + ww; if (wc > 111) wc = 111;
        gll16(xbase + ((size_t)(hc*W_IN + wc))*128 + ph*64 + sub*8, &smX[ci*8]);
      }
    }
  }

  // per-wave A base; slice stride 8192 shorts
  const unsigned short* Aw = F + wm*2048 + lane*8;

  // boff for step S
  auto BOFF = [&](int S) {
    const int ph  = (S >= 18);
    const int jj  = S - ph*18;
    const int rs  = jj >> 1, ch2 = jj & 1;
    const int r   = rs/3, s = rs - r*3;
    const int key = ((l15 + s) & 7) << 3;
    return ph*20736 + (r*18 + s)*64 + ((ch2*32 + lhi*8) ^ key);
  };

  short8 aP[4], aQ[4], bP[8], bQ[8];

  // prefetch a(0) while halo is in flight (global->reg, independent of LDS)
  #pragma unroll
  for (int u = 0; u < 4; ++u)
    aP[u] = *(const short8*)(Aw + u*512);

  __syncthreads();   // only barrier: halo landed

  // b(0) from LDS
  {
    const int boff = BOFF(0);
    #pragma unroll
    for (int nt = 0; nt < 8; ++nt)
      bP[nt] = *(const short8*)&smX[browb[nt] + boff];
  }

#define MFMAS(A, B)                                                              \
  {                                                                              \
    __builtin_amdgcn_s_setprio(1);                                               \
    _Pragma("unroll")                                                            \
    for (int nt = 0; nt < 8; ++nt) {                                             \
      _Pragma("unroll")                                                          \
      for (int mt = 0; mt < 4; ++mt)                                             \
        acc[mt][nt] = __builtin_amdgcn_mfma_f32_16x16x32_bf16(A[mt], B[nt], acc[mt][nt], 0, 0, 0); \
    }                                                                            \
    __builtin_amdgcn_s_setprio(0);                                               \
  }

  for (int i = 0; i < 36; i += 2) {
    // issue operand streams for step i+1 (awaited one MFMA cluster later)
    {
      const unsigned short* As = Aw + (size_t)(i + 1)*8192;
      #pragma unroll
      for (int u = 0; u < 4; ++u)
        aQ[u] = *(const short8*)(As + u*512);
      const int boff = BOFF(i + 1);
      #pragma unroll
      for (int nt = 0; nt < 8; ++nt)
        bQ[nt] = *(const short8*)&smX[browb[nt] + boff];
    }
    MFMAS(aP, bP);
    // issue streams for step i+2
    if (i + 2 < 36) {
      const unsigned short* As = Aw + (size_t)(i + 2)*8192;
      #pragma unroll
      for (int u = 0; u < 4; ++u)
        aP[u] = *(const short8*)(As + u*512);
      const int boff = BOFF(i + 2);
      #pragma unroll
      for (int nt = 0; nt < 8; ++nt)
        bP[nt] = *(const short8*)&smX[browb[nt] + boff];
    }
    MFMAS(aQ, bQ);
  }
#undef MFMAS

  // epilogue: D frag: col(px)=l15, row(k)=lhi*4+reg
  const int wv = w0 + l15;
  #pragma unroll
  for (int nt = 0; nt < 8; ++nt) {
    int hv = h0 + wn*8 + nt;
    if (hv < H_OUTD && wv < W_OUTD) {
      float* po = out + (size_t)n*K_OUT*(H_OUTD*W_OUTD) + hv*W_OUTD + wv;
      #pragma unroll
      for (int mt = 0; mt < 4; ++mt) {
        #pragma unroll
        for (int reg = 0; reg < 4; ++reg) {
          int k = wm*64 + mt*16 + lhi*4 + reg;
          po[(size_t)k*(H_OUTD*W_OUTD)] = acc[mt][nt][reg];
        }
      }
    }
  }
}

// ---------------- fallback (ws too small): naive fp32 ----------------
__global__ void naive_conv(const float* __restrict__ x, const float* __restrict__ ft,
                           float* __restrict__ out) {
  int idx = blockIdx.x*256 + threadIdx.x;
  int total = NBATCH*K_OUT*H_OUTD*W_OUTD;
  if (idx >= total) return;
  int w = idx % W_OUTD; int t = idx / W_OUTD;
  int h = t % H_OUTD; t /= H_OUTD;
  int k = t % K_OUT; int nn = t / K_OUT;
  float acc = 0.f;
  for (int c = 0; c < C_IN; ++c)
    for (int r = 0; r < 3; ++r)
      for (int s = 0; s < 3; ++s)
        acc += x[((size_t)(nn*C_IN + c)*H_IN + h + r)*W_IN + w + s]
             * ft[((k*C_IN + c)*3 + r)*3 + s];
  out[idx] = acc;
}

extern "C" void kernel_launch(void* const* d_in, const int* in_sizes, int n_in,
                              void* d_out, int out_size, void* d_ws, size_t ws_size,
                              hipStream_t stream) {
  (void)in_sizes; (void)n_in; (void)out_size;
  const float* x  = (const float*)d_in[0];
  const float* ft = (const float*)d_in[1];
  float* out = (float*)d_out;
  size_t need = (size_t)(XT_ELEMS + F_ELEMS) * sizeof(unsigned short);
  if (ws_size >= need) {
    unsigned short* xT = (unsigned short*)d_ws;
    unsigned short* F  = xT + XT_ELEMS;
    xpose_kernel<<<dim3(112, 32), 256, 0, stream>>>(x, xT);
    fprep_kernel<<<dim3(1152), 256, 0, stream>>>(ft, F);
    conv_gemm<<<dim3(49, 32), 512, 0, stream>>>(xT, F, out);
  } else {
    int total = NBATCH*K_OUT*H_OUTD*W_OUTD;
    naive_conv<<<(total + 255)/256, 256, 0, stream>>>(x, ft, out);
  }
}

// Round 14
// 311.076 us; speedup vs baseline: 1.1567x; 1.1149x over previous
//
#include <hip/hip_runtime.h>

typedef short short8 __attribute__((ext_vector_type(8)));
typedef float f32x4 __attribute__((ext_vector_type(4)));
typedef unsigned int uint;

#define C_IN  128
#define H_IN  112
#define W_IN  112
#define K_OUT 256
#define H_OUTD 110
#define W_OUTD 110
#define NBATCH 32

// xT layout: [n][h][w][cpos(128)] bf16, cpos = (c&64) | ((c&63) ^ ((w&7)<<3))
#define XT_ELEMS (NBATCH*H_IN*W_IN*128)    // 51,380,224
// F2 layout: [S(36)][wm(4)][mt(4)][lane(64)][e(8)], S = ph*18 + rs*2 + ch2
//   k = wm*64+mt*16+(lane&15) ; c = ph*64 + ch2*32 + (lane>>4)*8 + e
#define F_ELEMS  (36*4*4*64*8)             // 294,912

__device__ __forceinline__ unsigned short f2bf(float f) {
  uint u = __float_as_uint(f);
  u += 0x7fffu + ((u >> 16) & 1u);   // RNE
  return (unsigned short)(u >> 16);
}

__device__ __forceinline__ void gll16(const unsigned short* g, unsigned short* l) {
  __builtin_amdgcn_global_load_lds(
      (const __attribute__((address_space(1))) void*)g,
      (__attribute__((address_space(3))) void*)(uint)(uintptr_t)l, 16, 0, 0);
}

// ---------------- prep: x (NCHW f32) -> xT (swizzled bf16) ----------------
// LDS rows rotated by (w&15)*8 shorts to break the 32-way write conflict
// (lanes = consecutive w at 256B stride); phase 2 un-rotates (8-short step
// keeps 16B alignment, no wrap straddle).
__global__ __launch_bounds__(256) void xpose_kernel(const float* __restrict__ x,
                                                    unsigned short* __restrict__ xT) {
  __shared__ unsigned short sm[H_IN * 128];   // [w][cpos_rot] 28,672 B
  const int n = blockIdx.y;
  const int h = blockIdx.x;
  const int tid = threadIdx.x;
  for (int it = 0; it < 28; ++it) {
    int idx = it*256 + tid;            // 0..7167  (64 c-pairs x 112 w)
    int w  = idx % 112;
    int cp = idx / 112;                // 0..63
    int c0 = cp*2;
    const float* px = x + ((size_t)(n*C_IN + c0)*H_IN + h)*W_IN + w;
    float f0 = px[0];
    float f1 = px[H_IN*W_IN];
    uint key  = ((uint)w & 7u) << 3;
    uint cpos = ((uint)c0 & 64u) | (((uint)c0 & 63u) ^ key);
    uint crot = (cpos + ((uint)w & 15u)*8u) & 127u;
    uint v = (uint)f2bf(f0) | ((uint)f2bf(f1) << 16);
    *(uint*)&sm[w*128 + crot] = v;
  }
  __syncthreads();
  for (int it = 0; it < 7; ++it) {
    int idx = it*256 + tid;            // 0..1791 chunks of 8 shorts
    int w  = idx >> 4;
    int cc = idx & 15;
    uint base = ((uint)(cc*8) + ((uint)w & 15u)*8u) & 127u;
    uint4 v = *(const uint4*)&sm[w*128 + base];
    size_t off = (((size_t)n*H_IN + h)*W_IN + w)*128 + cc*8;
    *(uint4*)&xT[off] = v;
  }
}

// ---- prep: filt (OIHW f32) -> F2 fragment-packed bf16 (ph-major slices) ----
__global__ __launch_bounds__(256) void fprep_kernel(const float* __restrict__ ft,
                                                    unsigned short* __restrict__ F) {
  int idx = blockIdx.x*256 + threadIdx.x;   // < 294912
  int e    = idx & 7;
  int lane = (idx >> 3) & 63;
  int mt   = (idx >> 9) & 3;
  int wm   = (idx >> 11) & 3;
  int S    = idx >> 13;                     // 0..35
  int ph   = S >= 18;
  int j    = S - ph*18;
  int rs   = j >> 1;
  int ch2  = j & 1;
  int k = wm*64 + mt*16 + (lane & 15);
  int c = ph*64 + ch2*32 + (lane >> 4)*8 + e;
  F[idx] = f2bf(ft[(k*C_IN + c)*9 + rs]);
}

// ---------------- main implicit-GEMM conv: small-block cross-step reg pipeline ----------------
// block: 256 thr (4 waves, 4M x 1N), output tile = 256 K_out x (8h x 16w)
// wave = 64k x 128px (4 mt x 8 nt), acc = 128 regs; A has NO wn-duplication.
// smX halo 10x18, [ph(2)][cell(180)][64] = 46,080 B -> 2 independent blocks/CU:
// one block's K-loop hides the other's prologue staging + epilogue writes.
// NO barriers in K-loop; both operand streams reg-double-buffered (R13 body).
__global__ __launch_bounds__(256, 2) void conv_gemm(const unsigned short* __restrict__ xT,
                                                    const unsigned short* __restrict__ F,
                                                    float* __restrict__ out) {
  __shared__ unsigned short smX[2*180*64];    // 46,080 B
  // bijective XCD swizzle: 3136 blocks = 8 XCDs x 392
  const int bid  = blockIdx.y*98 + blockIdx.x;
  const int wgid = (bid & 7)*392 + (bid >> 3);
  const int tile = wgid % 98;                 // 14 h-tiles x 7 w-tiles
  const int n    = wgid / 98;
  const int tid  = threadIdx.x;
  const int lane = tid & 63;
  const int wm   = tid >> 6;                  // 0..3 (M quadrant, 64 k each)
  const int l15  = lane & 15;
  const int lhi  = lane >> 4;                 // 0..3
  const int th   = tile / 7;
  const int tw   = tile - th*7;
  const int h0   = th*8;
  const int w0   = tw*16;

  int browb[8];
  #pragma unroll
  for (int nt = 0; nt < 8; ++nt)
    browb[nt] = (nt*18 + l15)*64;             // halo cell * 64 shorts

  f32x4 acc[4][8];
  #pragma unroll
  for (int mt = 0; mt < 4; ++mt)
    #pragma unroll
    for (int nt = 0; nt < 8; ++nt)
      acc[mt][nt] = (f32x4){0.f, 0.f, 0.f, 0.f};

  // stage halo: 2880 chunks of 16B -> smX[ph][cell][64]
  {
    const unsigned short* xbase = xT + (size_t)n*H_IN*W_IN*128;
    #pragma unroll
    for (int k = 0; k < 12; ++k) {
      int ci = k*256 + tid;
      if (ci < 2880) {
        int ph  = ci >= 1440;
        int rem = ci - ph*1440;
        int cell = rem >> 3, sub = rem & 7;
        int hh = cell / 18, ww = cell - hh*18;
        int hc = h0 + hh; if (hc > 111) hc = 111;
        int wc = w0 + ww; if (wc > 111) wc = 111;
        gll16(xbase + ((size_t)(hc*W_IN + wc))*128 + ph*64 + sub*8, &smX[ci*8]);
      }
    }
  }

  // per-wave A base; slice stride 8192 shorts
  const unsigned short* Aw = F + wm*2048 + lane*8;

  auto BOFF = [&](int S) {
    const int ph  = (S >= 18);
    const int jj  = S - ph*18;
    const int rs  = jj >> 1, ch2 = jj & 1;
    const int r   = rs/3, s = rs - r*3;
    const int key = ((l15 + s) & 7) << 3;
    return ph*11520 + (r*18 + s)*64 + ((ch2*32 + lhi*8) ^ key);
  };

  short8 aP[4], aQ[4], bP[8], bQ[8];

  // prefetch a(0) while halo is in flight (global->reg, independent of LDS)
  #pragma unroll
  for (int u = 0; u < 4; ++u)
    aP[u] = *(const short8*)(Aw + u*512);

  __syncthreads();   // only barrier: halo landed

  {
    const int boff = BOFF(0);
    #pragma unroll
    for (int nt = 0; nt < 8; ++nt)
      bP[nt] = *(const short8*)&smX[browb[nt] + boff];
  }

#define MFMAS(A, B)                                                              \
  {                                                                              \
    __builtin_amdgcn_s_setprio(1);                                               \
    _Pragma("unroll")                                                            \
    for (int nt = 0; nt < 8; ++nt) {                                             \
      _Pragma("unroll")                                                          \
      for (int mt = 0; mt < 4; ++mt)                                             \
        acc[mt][nt] = __builtin_amdgcn_mfma_f32_16x16x32_bf16(A[mt], B[nt], acc[mt][nt], 0, 0, 0); \
    }                                                                            \
    __builtin_amdgcn_s_setprio(0);                                               \
  }

  for (int i = 0; i < 36; i += 2) {
    {
      const unsigned short* As = Aw + (size_t)(i + 1)*8192;
      #pragma unroll
      for (int u = 0; u < 4; ++u)
        aQ[u] = *(const short8*)(As + u*512);
      const int boff = BOFF(i + 1);
      #pragma unroll
      for (int nt = 0; nt < 8; ++nt)
        bQ[nt] = *(const short8*)&smX[browb[nt] + boff];
    }
    MFMAS(aP, bP);
    if (i + 2 < 36) {
      const unsigned short* As = Aw + (size_t)(i + 2)*8192;
      #pragma unroll
      for (int u = 0; u < 4; ++u)
        aP[u] = *(const short8*)(As + u*512);
      const int boff = BOFF(i + 2);
      #pragma unroll
      for (int nt = 0; nt < 8; ++nt)
        bP[nt] = *(const short8*)&smX[browb[nt] + boff];
    }
    MFMAS(aQ, bQ);
  }
#undef MFMAS

  // epilogue: D frag: col(px)=l15, row(k)=lhi*4+reg
  const int wv = w0 + l15;
  #pragma unroll
  for (int nt = 0; nt < 8; ++nt) {
    int hv = h0 + nt;
    if (hv < H_OUTD && wv < W_OUTD) {
      float* po = out + (size_t)n*K_OUT*(H_OUTD*W_OUTD) + hv*W_OUTD + wv;
      #pragma unroll
      for (int mt = 0; mt < 4; ++mt) {
        #pragma unroll
        for (int reg = 0; reg < 4; ++reg) {
          int k = wm*64 + mt*16 + lhi*4 + reg;
          po[(size_t)k*(H_OUTD*W_OUTD)] = acc[mt][nt][reg];
        }
      }
    }
  }
}

// ---------------- fallback (ws too small): naive fp32 ----------------
__global__ void naive_conv(const float* __restrict__ x, const float* __restrict__ ft,
                           float* __restrict__ out) {
  int idx = blockIdx.x*256 + threadIdx.x;
  int total = NBATCH*K_OUT*H_OUTD*W_OUTD;
  if (idx >= total) return;
  int w = idx % W_OUTD; int t = idx / W_OUTD;
  int h = t % H_OUTD; t /= H_OUTD;
  int k = t % K_OUT; int nn = t / K_OUT;
  float acc = 0.f;
  for (int c = 0; c < C_IN; ++c)
    for (int r = 0; r < 3; ++r)
      for (int s = 0; s < 3; ++s)
        acc += x[((size_t)(nn*C_IN + c)*H_IN + h + r)*W_IN + w + s]
             * ft[((k*C_IN + c)*3 + r)*3 + s];
  out[idx] = acc;
}

extern "C" void kernel_launch(void* const* d_in, const int* in_sizes, int n_in,
                              void* d_out, int out_size, void* d_ws, size_t ws_size,
                              hipStream_t stream) {
  (void)in_sizes; (void)n_in; (void)out_size;
  const float* x  = (const float*)d_in[0];
  const float* ft = (const float*)d_in[1];
  float* out = (float*)d_out;
  size_t need = (size_t)(XT_ELEMS + F_ELEMS) * sizeof(unsigned short);
  if (ws_size >= need) {
    unsigned short* xT = (unsigned short*)d_ws;
    unsigned short* F  = xT + XT_ELEMS;
    xpose_kernel<<<dim3(112, 32), 256, 0, stream>>>(x, xT);
    fprep_kernel<<<dim3(1152), 256, 0, stream>>>(ft, F);
    conv_gemm<<<dim3(98, 32), 256, 0, stream>>>(xT, F, out);
  } else {
    int total = NBATCH*K_OUT*H_OUTD*W_OUTD;
    naive_conv<<<(total + 255)/256, 256, 0, stream>>>(x, ft, out);
  }
}